// Round 11
// baseline (220.040 us; speedup 1.0000x reference)
//
#include <hip/hip_runtime.h>
#include <hip/hip_fp16.h>
#include <math.h>

#define NPROJ 96
#define NANG  96
#define DET   192
#define NPIX  16384            // 128*128
#define SLICE (NANG*DET)       // 18432

// DSD/DU = DSD/DV = 1000/3.5
#define KPROJ 285.7142857142857f

__device__ __forceinline__ float frcp(float x) { return __builtin_amdgcn_rcpf(x); }

__device__ __forceinline__ float ffract(float x) {
#if __has_builtin(__builtin_amdgcn_fractf)
    return __builtin_amdgcn_fractf(x);
#else
    return x - floorf(x);
#endif
}

typedef __fp16 h2 __attribute__((ext_vector_type(2)));

__device__ __forceinline__ unsigned pack2(float a, float b) {
    h2 p = __builtin_amdgcn_cvt_pkrtz(a, b);
    return __builtin_bit_cast(unsigned, p);
}
__device__ __forceinline__ h2 as_h2(unsigned u) { return __builtin_bit_cast(h2, u); }

#if __has_builtin(__builtin_amdgcn_fdot2)
#define FDOT2(a, b, c) __builtin_amdgcn_fdot2((a), (b), (c), false)
#else
__device__ __forceinline__ float FDOT2(h2 a, h2 b, float c) {
    return c + (float)a[0] * (float)b[0] + (float)a[1] * (float)b[1];
}
#endif

// ---------------------------------------------------------------------------
// K1a: deriv -> OVERLAPPING uint2 quads: derivq[row][d] = (pr(d), pr(d+1))
// where pr(d) = half2(g[d], g[d+1]). 8B-aligned dwordx2 gather target.
// ---------------------------------------------------------------------------
__global__ __launch_bounds__(192) void k_deriv2(const float* __restrict__ sino,
                                                const float* __restrict__ wgt,
                                                uint2* __restrict__ derivq) {
    __shared__ float row[DET];
    const int r = blockIdx.x;          // p*96 + a
    const int d = threadIdx.x;         // 0..191
    const int base = r * DET + d;
    row[d] = sino[base] * wgt[base];
    __syncthreads();
    auto grad = [&](int i) -> float {
        i = (i > DET-1) ? DET-1 : i;
        if (i == 0)       return row[1] - row[0];
        if (i == DET-1)   return row[DET-1] - row[DET-2];
        return 0.5f * (row[i+1] - row[i-1]);
    };
    const float g0 = grad(d), g1 = grad(d+1), g2 = grad(d+2);
    derivq[base] = make_uint2(pack2(g0, g1), pack2(g1, g2));
}

// K1b: fallback pair layout (dword per d), used if ws too small.
__global__ __launch_bounds__(192) void k_deriv(const float* __restrict__ sino,
                                               const float* __restrict__ wgt,
                                               unsigned* __restrict__ derivp) {
    __shared__ float row[DET];
    const int r = blockIdx.x;
    const int d = threadIdx.x;
    const int base = r * DET + d;
    row[d] = sino[base] * wgt[base];
    __syncthreads();
    auto grad = [&](int i) -> float {
        i = (i > DET-1) ? DET-1 : i;
        if (i == 0)       return row[1] - row[0];
        if (i == DET-1)   return row[DET-1] - row[DET-2];
        return 0.5f * (row[i+1] - row[i-1]);
    };
    derivp[base] = pack2(grad(d), grad(d+1));
}

// ---------------------------------------------------------------------------
// Shared bp2d epilogue: cosine-weight + write EVEN-BASE v-quad layout:
//   wcbq[p][vq][u] (uint4) slots k=0..3 hold pr(2vq+k, u),
//   pr(v,u) = half2(w[v][u], w[v][u+1]).
// Each pixel row v writes its pr into 2 quads: (v>>1, slot v&1) and
// (v>>1 - 1, slot (v&1)+2).
// ---------------------------------------------------------------------------
__device__ __forceinline__ void bp2d_epilogue(float* buf, int tid, int pixbase,
                                              int p, unsigned* wcbq_dw) {
    __syncthreads();
    unsigned* sq = wcbq_dw + p * 32768;   // 64*128*4 dwords per slice
    #pragma unroll
    for (int i = 0; i < 2; ++i) {
        const int l   = 2*tid + i;
        const int pix = pixbase + l;
        const int u   = pix & 127;
        const int v   = pix >> 7;
        const float v0 = buf[l];
        const float v1 = (u < 127) ? buf[l + 1] : 0.0f;   // u=127 pair unused
        const unsigned pr = pack2(v0, v1);
        const int vq1 = v >> 1, k1 = v & 1;
        sq[(((vq1 << 7) + u) << 2) + k1] = pr;
        const int vq2 = vq1 - 1;
        if (vq2 >= 0) sq[(((vq2 << 7) + u) << 2) + k1 + 2] = pr;
    }
}

// ---------------------------------------------------------------------------
// K2a: 2D backprojection, x-PAIR SHARED loads: thread handles 2 x-adjacent
// pixels; |pos1-pos0| = |cos| <= 1 so both pair-taps sit in ONE dwordx2
// from the overlapping derivq -> loads halve (96/thread). No masks.
// ---------------------------------------------------------------------------
__global__ __launch_bounds__(256) void k_bp2d_pair(const uint2* __restrict__ derivq,
                                                   unsigned* __restrict__ wcbq_dw) {
    __shared__ float sc[NANG], ss[NANG];
    __shared__ float buf[512];
    const int p   = blockIdx.x;
    const int tid = threadIdx.x;

    if (tid < NANG) {
        float s_, c_;
        sincosf((float)tid * (float)(3.14159265358979323846 / 96.0), &s_, &c_);
        sc[tid] = c_; ss[tid] = s_;
    }

    const int pixbase = blockIdx.y * 512;
    const int px0 = pixbase + 2*tid;       // even x
    const float fx0 = (float)(px0 & 127) - 63.5f;
    const float fy  = (float)(px0 >> 7)  - 63.5f;
    float acc0 = 0.0f, acc1 = 0.0f;
    __syncthreads();   // trig ready

    const uint2* rowq = derivq + p * SLICE;
    for (int a = 0; a < NANG; ++a, rowq += DET) {
        const float cb = sc[a], sb = ss[a];
        const float pos0 = fmaf(cb, fx0, fmaf(sb, fy, 95.5f));
        const float pos1 = pos0 + cb;
        const int i0 = (int)pos0;
        const int i1 = (int)pos1;
        const int m  = (i0 < i1) ? i0 : i1;
        const uint2 q = rowq[m];           // (pr(m), pr(m+1)), 8B aligned
        const unsigned pa = (i0 == m) ? q.x : q.y;
        const unsigned pb = (i1 == m) ? q.x : q.y;
        const float f0 = ffract(pos0);
        const float f1 = ffract(pos1);
        acc0 = FDOT2(as_h2(pa), as_h2(pack2(1.0f - f0, f0)), acc0);
        acc1 = FDOT2(as_h2(pb), as_h2(pack2(1.0f - f1, f1)), acc1);
    }

    const float fx1 = fx0 + 1.0f;
    buf[2*tid]     = acc0 * (1000.0f * rsqrtf(1000000.0f + fx0*fx0 + fy*fy));
    buf[2*tid + 1] = acc1 * (1000.0f * rsqrtf(1000000.0f + fx1*fx1 + fy*fy));
    bp2d_epilogue(buf, tid, pixbase, p, wcbq_dw);
}

// K2b: fallback — per-pixel dword loads from pair-layout derivp.
__global__ __launch_bounds__(256) void k_bp2d_fb(const unsigned* __restrict__ derivp,
                                                 unsigned* __restrict__ wcbq_dw) {
    __shared__ float sc[NANG], ss[NANG];
    __shared__ float buf[512];
    const int p   = blockIdx.x;
    const int tid = threadIdx.x;
    if (tid < NANG) {
        float s_, c_;
        sincosf((float)tid * (float)(3.14159265358979323846 / 96.0), &s_, &c_);
        sc[tid] = c_; ss[tid] = s_;
    }
    const int pixbase = blockIdx.y * 512;
    const int px0 = pixbase + 2*tid;
    const float fx0 = (float)(px0 & 127) - 63.5f;
    const float fy  = (float)(px0 >> 7)  - 63.5f;
    float acc0 = 0.0f, acc1 = 0.0f;
    __syncthreads();
    const unsigned* rowp = derivp + p * SLICE;
    for (int a = 0; a < NANG; ++a, rowp += DET) {
        const float cb = sc[a], sb = ss[a];
        const float pos0 = fmaf(cb, fx0, fmaf(sb, fy, 95.5f));
        const float pos1 = pos0 + cb;
        const int i0 = (int)pos0;
        const int i1 = (int)pos1;
        const float f0 = ffract(pos0);
        const float f1 = ffract(pos1);
        acc0 = FDOT2(as_h2(rowp[i0]), as_h2(pack2(1.0f - f0, f0)), acc0);
        acc1 = FDOT2(as_h2(rowp[i1]), as_h2(pack2(1.0f - f1, f1)), acc1);
    }
    const float fx1 = fx0 + 1.0f;
    buf[2*tid]     = acc0 * (1000.0f * rsqrtf(1000000.0f + fx0*fx0 + fy*fy));
    buf[2*tid + 1] = acc1 * (1000.0f * rsqrtf(1000000.0f + fx1*fx1 + fy*fy));
    bp2d_epilogue(buf, tid, pixbase, p, wcbq_dw);
}

// ---------------------------------------------------------------------------
// K3: 3D cone-beam backprojection + PReLU — EVEN-BASE v-quad loads:
// Kz < 0.7 guarantees a z-pair's 4 bilinear rows fit in the 4-row quad at
// base ivA&~1 -> ONE dwordx4 per 2 z = 2 loads/beta (was 4).
// grid (64 y-pairs, 32 z-chunks) = 2048 blocks = 8/CU. No masks.
// ---------------------------------------------------------------------------
__global__ __launch_bounds__(256) void k_bp3d(const uint4* __restrict__ wcbq,
                                              const float* __restrict__ prelu,
                                              float* __restrict__ out) {
    __shared__ float sc[NPROJ], ss[NPROJ];
    const int tid = threadIdx.x;
    const int x   = tid & 127;
    const int y   = (blockIdx.x << 1) | (tid >> 7);
    const int z0  = blockIdx.y << 2;

    if (tid < NPROJ) {
        float s_, c_;
        sincosf((float)tid * (float)(2.0 * 3.14159265358979323846 / 96.0), &s_, &c_);
        sc[tid] = c_; ss[tid] = s_;
    }

    const float fx  = (float)x - 63.5f;
    const float fy  = (float)y - 63.5f;
    const float zlo = (float)z0 - 63.5f;

    float acc[4];
    #pragma unroll
    for (int j = 0; j < 4; ++j) acc[j] = 0.0f;

    __syncthreads();   // trig ready — the only barrier

    const uint4* bb = wcbq;              // per-beta slice = 64*128 uint4
    for (int b = 0; b < NPROJ; ++b, bb += 8192) {
        const float cb    = sc[b], sb = ss[b];
        const float t     = fmaf(fx, cb,  fy * sb);
        const float sdist = fmaf(fy, cb, -fx * sb);
        const float invr  = frcp(500.0f + t);
        const float pu    = fmaf(KPROJ * sdist, invr, 63.5f);
        const int   iu0   = (int)pu;             // pu in [11, 116]
        const float fu    = ffract(pu);
        float w2 = 1000.0f * invr; w2 *= w2;
        const float Kz    = KPROJ * invr;
        const h2    wu    = as_h2(pack2(1.0f - fu, fu));   // z-invariant

        #pragma unroll
        for (int pr2 = 0; pr2 < 2; ++pr2) {      // z-pairs (0,1) and (2,3)
            const float pvA = fmaf(Kz, zlo + (float)(2*pr2),     63.5f);
            const float pvB = fmaf(Kz, zlo + (float)(2*pr2 + 1), 63.5f);
            const int   ivA = (int)pvA;          // pv in [19, 108]
            const int   ivB = (int)pvB;          // ivB in {ivA, ivA+1}
            const float fvA = ffract(pvA);
            const float fvB = ffract(pvB);
            const int   bqi = ivA >> 1;
            const int   s   = ivA & 1;           // slot of row ivA
            const int   dS  = ivB - (bqi << 1);  // slot of row ivB, in {s, s+1}
            const uint4 q   = bb[(bqi << 7) + iu0];
            const unsigned topA = s ? q.y : q.x;
            const unsigned botA = s ? q.z : q.y;
            unsigned topB = (dS >= 1) ? q.y : q.x;  topB = (dS >= 2) ? q.z : topB;
            unsigned botB = (dS >= 1) ? q.z : q.y;  botB = (dS >= 2) ? q.w : botB;
            const float tA = FDOT2(as_h2(topA), wu, 0.0f);
            const float bA = FDOT2(as_h2(botA), wu, 0.0f);
            acc[2*pr2]     = fmaf(fmaf(fvA, bA - tA, tA), w2, acc[2*pr2]);
            const float tB = FDOT2(as_h2(topB), wu, 0.0f);
            const float bB = FDOT2(as_h2(botB), wu, 0.0f);
            acc[2*pr2 + 1] = fmaf(fmaf(fvB, bB - tB, tB), w2, acc[2*pr2 + 1]);
        }
    }

    const float a = prelu[0];
    #pragma unroll
    for (int j = 0; j < 4; ++j) {
        const float v = acc[j];
        out[((z0 + j) << 14) + (y << 7) + x] = (v >= 0.0f) ? v : a * v;
    }
}

// ---------------------------------------------------------------------------
extern "C" void kernel_launch(void* const* d_in, const int* in_sizes, int n_in,
                              void* d_out, int out_size, void* d_ws, size_t ws_size,
                              hipStream_t stream) {
    const float* sino  = (const float*)d_in[0];   // (1,1,96,96,192)
    const float* wgt   = (const float*)d_in[1];   // (1,96,96,192)
    const float* prelu = (const float*)d_in[2];   // (1,)
    float* out = (float*)d_out;                   // 128^3 floats

    const size_t wcbq_bytes = (size_t)NPROJ * 64 * 128 * 16;   // 12.58 MB
    unsigned* wcbq_dw = (unsigned*)d_ws;
    char*     deriv_p = (char*)d_ws + wcbq_bytes;
    const size_t need_primary = wcbq_bytes + (size_t)NPROJ * SLICE * 8;  // +14.16 MB

    if (ws_size >= need_primary) {
        k_deriv2<<<dim3(NPROJ * NANG), dim3(192), 0, stream>>>(sino, wgt, (uint2*)deriv_p);
        k_bp2d_pair<<<dim3(NPROJ, 32), dim3(256), 0, stream>>>((const uint2*)deriv_p, wcbq_dw);
    } else {
        k_deriv<<<dim3(NPROJ * NANG), dim3(192), 0, stream>>>(sino, wgt, (unsigned*)deriv_p);
        k_bp2d_fb<<<dim3(NPROJ, 32), dim3(256), 0, stream>>>((const unsigned*)deriv_p, wcbq_dw);
    }
    k_bp3d<<<dim3(64, 32), dim3(256), 0, stream>>>((const uint4*)wcbq_dw, prelu, out);
}

// Round 12
// 200.278 us; speedup vs baseline: 1.0987x; 1.0987x over previous
//
#include <hip/hip_runtime.h>
#include <hip/hip_fp16.h>
#include <math.h>

#define NPROJ 96
#define NANG  96
#define DET   192
#define NPIX  16384            // 128*128
#define SLICE (NANG*DET)       // 18432

// DSD/DU = DSD/DV = 1000/3.5
#define KPROJ 285.7142857142857f

__device__ __forceinline__ float frcp(float x) { return __builtin_amdgcn_rcpf(x); }

__device__ __forceinline__ float ffract(float x) {
#if __has_builtin(__builtin_amdgcn_fractf)
    return __builtin_amdgcn_fractf(x);
#else
    return x - floorf(x);
#endif
}

typedef __fp16 h2 __attribute__((ext_vector_type(2)));

__device__ __forceinline__ unsigned pack2(float a, float b) {
    h2 p = __builtin_amdgcn_cvt_pkrtz(a, b);
    return __builtin_bit_cast(unsigned, p);
}
__device__ __forceinline__ h2 as_h2(unsigned u) { return __builtin_bit_cast(h2, u); }

#if __has_builtin(__builtin_amdgcn_fdot2)
#define FDOT2(a, b, c) __builtin_amdgcn_fdot2((a), (b), (c), false)
#else
__device__ __forceinline__ float FDOT2(h2 a, h2 b, float c) {
    return c + (float)a[0] * (float)b[0] + (float)a[1] * (float)b[1];
}
#endif

// ---------------------------------------------------------------------------
// K1: deriv = grad_lastdim(sino * weight) -> packed fp16 PAIRS:
// derivp[row][d] = half2(g[d], g[d+1]).
// ---------------------------------------------------------------------------
__global__ __launch_bounds__(192) void k_deriv(const float* __restrict__ sino,
                                               const float* __restrict__ wgt,
                                               unsigned* __restrict__ derivp) {
    __shared__ float row[DET];
    const int r = blockIdx.x;          // p*96 + a
    const int d = threadIdx.x;         // 0..191
    const int base = r * DET + d;
    row[d] = sino[base] * wgt[base];
    __syncthreads();
    float g0, g1;
    if (d == 0)            g0 = row[1] - row[0];
    else if (d == DET-1)   g0 = row[DET-1] - row[DET-2];
    else                   g0 = 0.5f * (row[d+1] - row[d-1]);
    if (d >= DET-2)        g1 = (d == DET-1) ? 0.0f : row[DET-1] - row[DET-2];
    else                   g1 = 0.5f * (row[d+2] - row[d]);
    derivp[base] = pack2(g0, g1);
}

// ---------------------------------------------------------------------------
// K2: 2D backprojection + cosine weighting -> packed QUAD layout for bp3d:
//   wcb4[p][v][u] = uint2{ half2(w[v][u], w[v][u+1]), half2(w[v+1][u], w[v+1][u+1]) }
// (r8/r10 proven form: single angle per iter, 2 px/thread, 3072 blocks)
// pos in [5.7,185.3] -> no masks.
// ---------------------------------------------------------------------------
__global__ __launch_bounds__(256) void k_bp2d(const unsigned* __restrict__ derivp,
                                              unsigned* __restrict__ wcb4) {
    __shared__ float sc[NANG], ss[NANG];
    __shared__ float buf[512];
    const int p   = blockIdx.x;
    const int tid = threadIdx.x;

    if (tid < NANG) {
        float s_, c_;
        sincosf((float)tid * (float)(3.14159265358979323846 / 96.0), &s_, &c_);
        sc[tid] = c_; ss[tid] = s_;
    }

    const int pixbase = blockIdx.y * 512;
    float acc[2], fx[2], fy[2];
    #pragma unroll
    for (int i = 0; i < 2; ++i) {
        const int pix = pixbase + i*256 + tid;
        fx[i] = (float)(pix & 127) - 63.5f;
        fy[i] = (float)(pix >> 7)  - 63.5f;
        acc[i] = 0.0f;
    }
    __syncthreads();   // trig ready

    const unsigned* rowp = derivp + p * SLICE;   // advances by DET per angle
    for (int a = 0; a < NANG; ++a, rowp += DET) {
        const float cb = sc[a], sb = ss[a];
        #pragma unroll
        for (int i = 0; i < 2; ++i) {
            const float pos = fmaf(cb, fx[i], fmaf(sb, fy[i], 95.5f));
            const int   i0  = (int)pos;            // pos > 0 always
            const float f   = ffract(pos);
            const h2    g   = as_h2(rowp[i0]);     // (deriv[i0], deriv[i0+1])
            acc[i] = FDOT2(g, as_h2(pack2(1.0f - f, f)), acc[i]);
        }
    }

    // cosine-weight, pack (u,u+1) pairs via LDS, dual-store into quad layout
    #pragma unroll
    for (int i = 0; i < 2; ++i) {
        const float w = 1000.0f * rsqrtf(1000000.0f + fx[i]*fx[i] + fy[i]*fy[i]);
        buf[i*256 + tid] = acc[i] * w;
    }
    __syncthreads();
    unsigned* slice4 = wcb4 + p * (NPIX * 2);    // uint2 viewed as 2 dwords
    #pragma unroll
    for (int i = 0; i < 2; ++i) {
        const int l   = i*256 + tid;
        const int pix = pixbase + l;
        const int u   = pix & 127;
        const int v   = pix >> 7;
        const float v0 = buf[l];
        const float v1 = (u < 127) ? buf[l + 1] : 0.0f;   // u=127 pair unused
        const unsigned pr = pack2(v0, v1);
        slice4[pix * 2] = pr;                         // wcb4[v][u].x
        if (v >= 1) slice4[(pix - 128) * 2 + 1] = pr; // wcb4[v-1][u].y
    }
}

// ---------------------------------------------------------------------------
// K3: 3D cone-beam backprojection + PReLU — r8 structure, VALU diet:
//  * 8 z per thread: per-beta outer math amortized 2x vs r8
//  * w2 folded into packed u-weights (wuw): kills per-z *w2 fma
//  * ONE dwordx2 gather per voxel-beta (proven optimal: r9/r10/r11 showed
//    ILP, locality, and load-merging are all neutral-or-worse; VALU issue
//    is the binding pipe)
// grid (64 y-pairs, 16 z-chunks) = 1024 blocks, VGPR ~60 -> 8 waves/SIMD cap.
// pu in [11,116], pv in [19,108] -> no masks.
// ---------------------------------------------------------------------------
__global__ __launch_bounds__(256) void k_bp3d(const uint2* __restrict__ wcb4,
                                              const float* __restrict__ prelu,
                                              float* __restrict__ out) {
    __shared__ float sc[NPROJ], ss[NPROJ];
    const int tid = threadIdx.x;
    const int x   = tid & 127;
    const int y   = (blockIdx.x << 1) | (tid >> 7);
    const int z0  = blockIdx.y << 3;

    if (tid < NPROJ) {
        float s_, c_;
        sincosf((float)tid * (float)(2.0 * 3.14159265358979323846 / 96.0), &s_, &c_);
        sc[tid] = c_; ss[tid] = s_;
    }

    const float fx  = (float)x - 63.5f;
    const float fy  = (float)y - 63.5f;
    const float zlo = (float)z0 - 63.5f;

    float acc[8];
    #pragma unroll
    for (int j = 0; j < 8; ++j) acc[j] = 0.0f;

    __syncthreads();   // trig ready — the only barrier

    const uint2* bb = wcb4;              // uniform per-beta base (SGPR)
    for (int b = 0; b < NPROJ; ++b, bb += NPIX) {
        const float cb    = sc[b], sb = ss[b];
        const float t     = fmaf(fx, cb,  fy * sb);
        const float sdist = fmaf(fy, cb, -fx * sb);
        const float invr  = frcp(500.0f + t);
        const float pu    = fmaf(KPROJ * sdist, invr, 63.5f);
        const int   iu0   = (int)pu;             // pu in [11, 116]
        const float fu    = ffract(pu);
        float w2 = 1000.0f * invr; w2 *= w2;
        const float Kz    = KPROJ * invr;
        // u-weights with w2 folded in (fp16 rel 5e-4, values <= 2.56)
        const h2    wuw   = as_h2(pack2((1.0f - fu) * w2, fu * w2));

        int   off[8];
        float fv[8];
        #pragma unroll
        for (int j = 0; j < 8; ++j) {
            const float pv  = fmaf(Kz, zlo + (float)j, 63.5f);
            const int   iv0 = (int)pv;           // pv in [19, 108]
            fv[j]  = ffract(pv);
            off[j] = (iv0 << 7) + iu0;           // uint2-element offset
        }
        uint2 g[8];
        #pragma unroll
        for (int j = 0; j < 8; ++j) g[j] = bb[off[j]];   // all 4 taps, 8B
        #pragma unroll
        for (int j = 0; j < 8; ++j) {
            const float top = FDOT2(as_h2(g[j].x), wuw, 0.0f);
            const float bot = FDOT2(as_h2(g[j].y), wuw, 0.0f);
            acc[j] += fmaf(fv[j], bot - top, top);
        }
    }

    const float a = prelu[0];
    #pragma unroll
    for (int j = 0; j < 8; ++j) {
        const float v = acc[j];
        out[((z0 + j) << 14) + (y << 7) + x] = (v >= 0.0f) ? v : a * v;
    }
}

// ---------------------------------------------------------------------------
extern "C" void kernel_launch(void* const* d_in, const int* in_sizes, int n_in,
                              void* d_out, int out_size, void* d_ws, size_t ws_size,
                              hipStream_t stream) {
    const float* sino  = (const float*)d_in[0];   // (1,1,96,96,192)
    const float* wgt   = (const float*)d_in[1];   // (1,96,96,192)
    const float* prelu = (const float*)d_in[2];   // (1,)
    unsigned* derivp = (unsigned*)d_ws;           // 96*96*192 packed pairs
    unsigned* wcb4   = derivp + NPROJ * SLICE;    // 96*128*128 uint2 quads
    float* out = (float*)d_out;                   // 128^3 floats

    k_deriv<<<dim3(NPROJ * NANG), dim3(192), 0, stream>>>(sino, wgt, derivp);
    k_bp2d <<<dim3(NPROJ, 32),    dim3(256), 0, stream>>>(derivp, wcb4);
    k_bp3d <<<dim3(64, 16),       dim3(256), 0, stream>>>((const uint2*)wcb4, prelu, out);
}

// Round 13
// 193.269 us; speedup vs baseline: 1.1385x; 1.0363x over previous
//
#include <hip/hip_runtime.h>
#include <hip/hip_fp16.h>
#include <math.h>

#define NPROJ 96
#define NANG  96
#define DET   192
#define NPIX  16384            // 128*128
#define SLICE (NANG*DET)       // 18432

// DSD/DU = DSD/DV = 1000/3.5
#define KPROJ 285.7142857142857f

__device__ __forceinline__ float frcp(float x) { return __builtin_amdgcn_rcpf(x); }

__device__ __forceinline__ float ffract(float x) {
#if __has_builtin(__builtin_amdgcn_fractf)
    return __builtin_amdgcn_fractf(x);
#else
    return x - floorf(x);
#endif
}

typedef __fp16 h2 __attribute__((ext_vector_type(2)));

__device__ __forceinline__ unsigned pack2(float a, float b) {
    h2 p = __builtin_amdgcn_cvt_pkrtz(a, b);
    return __builtin_bit_cast(unsigned, p);
}
__device__ __forceinline__ h2 as_h2(unsigned u) { return __builtin_bit_cast(h2, u); }

#if __has_builtin(__builtin_amdgcn_fdot2)
#define FDOT2(a, b, c) __builtin_amdgcn_fdot2((a), (b), (c), false)
#else
__device__ __forceinline__ float FDOT2(h2 a, h2 b, float c) {
    return c + (float)a[0] * (float)b[0] + (float)a[1] * (float)b[1];
}
#endif

// ---------------------------------------------------------------------------
// K1: deriv = grad_lastdim(sino * weight) -> packed fp16 PAIRS:
// derivp[row][d] = half2(g[d], g[d+1]).
// ---------------------------------------------------------------------------
__global__ __launch_bounds__(192) void k_deriv(const float* __restrict__ sino,
                                               const float* __restrict__ wgt,
                                               unsigned* __restrict__ derivp) {
    __shared__ float row[DET];
    const int r = blockIdx.x;          // p*96 + a
    const int d = threadIdx.x;         // 0..191
    const int base = r * DET + d;
    row[d] = sino[base] * wgt[base];
    __syncthreads();
    float g0, g1;
    if (d == 0)            g0 = row[1] - row[0];
    else if (d == DET-1)   g0 = row[DET-1] - row[DET-2];
    else                   g0 = 0.5f * (row[d+1] - row[d-1]);
    if (d >= DET-2)        g1 = (d == DET-1) ? 0.0f : row[DET-1] - row[DET-2];
    else                   g1 = 0.5f * (row[d+2] - row[d]);
    derivp[base] = pack2(g0, g1);
}

// ---------------------------------------------------------------------------
// K2 core: 2D backprojection + cosine weighting (r8 proven main loop).
// Epilogue writes either the every-v QUAD layout (primary, for dwordx4 bp3d)
// or the uint2 pair layout (fallback).
//   quad: wq[p][v][u] = uint4( pr(v,u), pr(v+1,u), pr(v+2,u), pr(v+3,u) )
//   pr(v,u) = half2(w[v][u], w[v][u+1])
// ---------------------------------------------------------------------------
template <int QUAD>
__global__ __launch_bounds__(256) void k_bp2d_t(const unsigned* __restrict__ derivp,
                                                unsigned* __restrict__ dst) {
    __shared__ float sc[NANG], ss[NANG];
    __shared__ float buf[512];
    const int p   = blockIdx.x;
    const int tid = threadIdx.x;

    if (tid < NANG) {
        float s_, c_;
        sincosf((float)tid * (float)(3.14159265358979323846 / 96.0), &s_, &c_);
        sc[tid] = c_; ss[tid] = s_;
    }

    const int pixbase = blockIdx.y * 512;
    float acc[2], fx[2], fy[2];
    #pragma unroll
    for (int i = 0; i < 2; ++i) {
        const int pix = pixbase + i*256 + tid;
        fx[i] = (float)(pix & 127) - 63.5f;
        fy[i] = (float)(pix >> 7)  - 63.5f;
        acc[i] = 0.0f;
    }
    __syncthreads();   // trig ready

    const unsigned* rowp = derivp + p * SLICE;   // advances by DET per angle
    for (int a = 0; a < NANG; ++a, rowp += DET) {
        const float cb = sc[a], sb = ss[a];
        #pragma unroll
        for (int i = 0; i < 2; ++i) {
            const float pos = fmaf(cb, fx[i], fmaf(sb, fy[i], 95.5f));
            const int   i0  = (int)pos;            // pos > 0 always
            const float f   = ffract(pos);
            const h2    g   = as_h2(rowp[i0]);     // (deriv[i0], deriv[i0+1])
            acc[i] = FDOT2(g, as_h2(pack2(1.0f - f, f)), acc[i]);
        }
    }

    #pragma unroll
    for (int i = 0; i < 2; ++i) {
        const float w = 1000.0f * rsqrtf(1000000.0f + fx[i]*fx[i] + fy[i]*fy[i]);
        buf[i*256 + tid] = acc[i] * w;
    }
    __syncthreads();
    #pragma unroll
    for (int i = 0; i < 2; ++i) {
        const int l   = i*256 + tid;
        const int pix = pixbase + l;
        const int u   = pix & 127;
        const int v   = pix >> 7;
        const float v0 = buf[l];
        const float v1 = (u < 127) ? buf[l + 1] : 0.0f;   // u=127 pair unused
        const unsigned pr = pack2(v0, v1);
        if (QUAD) {
            unsigned* sq = dst + p * (NPIX * 4);          // 128*128 uint4 = dwords*4
            #pragma unroll
            for (int k = 0; k < 4; ++k) {                 // pr is row v: slot k of quad v-k
                const int vb = v - k;
                if (vb >= 0) sq[(((vb << 7) + u) << 2) + k] = pr;
            }
        } else {
            unsigned* s2 = dst + p * (NPIX * 2);
            s2[pix * 2] = pr;                             // wcb4[v][u].x
            if (v >= 1) s2[(pix - 128) * 2 + 1] = pr;     // wcb4[v-1][u].y
        }
    }
}

// ---------------------------------------------------------------------------
// K3 primary: every-v quad loads — ONE dwordx4 per z-PAIR (2 loads/beta for
// 4z vs r8's 4). z=A uses fixed slots q.x/q.y (zero selects); z=B needs one
// cmp + 2 cndmask (d = ivB-ivA in {0,1}; rows ivB,ivB+1 always inside the
// 4-row quad since ivB <= ivA+1). w2 folded into packed u-weights.
// grid (64 y-pairs, 32 z-chunks) = 2048 blocks = 32 waves/CU.
// pu in [11,116], pv in [19,108] -> no masks.
// ---------------------------------------------------------------------------
__global__ __launch_bounds__(256) void k_bp3d_q(const uint4* __restrict__ wq,
                                                const float* __restrict__ prelu,
                                                float* __restrict__ out) {
    __shared__ float sc[NPROJ], ss[NPROJ];
    const int tid = threadIdx.x;
    const int x   = tid & 127;
    const int y   = (blockIdx.x << 1) | (tid >> 7);
    const int z0  = blockIdx.y << 2;

    if (tid < NPROJ) {
        float s_, c_;
        sincosf((float)tid * (float)(2.0 * 3.14159265358979323846 / 96.0), &s_, &c_);
        sc[tid] = c_; ss[tid] = s_;
    }

    const float fx  = (float)x - 63.5f;
    const float fy  = (float)y - 63.5f;
    const float zlo = (float)z0 - 63.5f;

    float acc[4];
    #pragma unroll
    for (int j = 0; j < 4; ++j) acc[j] = 0.0f;

    __syncthreads();   // trig ready — the only barrier

    const uint4* bb = wq;                // per-beta slice = 128*128 uint4
    for (int b = 0; b < NPROJ; ++b, bb += NPIX) {
        const float cb    = sc[b], sb = ss[b];
        const float t     = fmaf(fx, cb,  fy * sb);
        const float sdist = fmaf(fy, cb, -fx * sb);
        const float invr  = frcp(500.0f + t);
        const float pu    = fmaf(KPROJ * sdist, invr, 63.5f);
        const int   iu0   = (int)pu;             // pu in [11, 116]
        const float fu    = ffract(pu);
        float w2 = 1000.0f * invr; w2 *= w2;
        const float Kz    = KPROJ * invr;
        const h2    wuw   = as_h2(pack2((1.0f - fu) * w2, fu * w2));

        #pragma unroll
        for (int pr2 = 0; pr2 < 2; ++pr2) {      // z-pairs (0,1), (2,3)
            const float pvA = fmaf(Kz, zlo + (float)(2*pr2), 63.5f);
            const float pvB = pvA + Kz;
            const int   ivA = (int)pvA;          // pv in [19, 108]
            const int   ivB = (int)pvB;          // ivA or ivA+1
            const float fvA = ffract(pvA);
            const float fvB = ffract(pvB);
            const uint4 q   = bb[(ivA << 7) + iu0];   // rows ivA..ivA+3
            const int   d   = ivB - ivA;              // 0 or 1
            const float tA  = FDOT2(as_h2(q.x), wuw, 0.0f);
            const float bA  = FDOT2(as_h2(q.y), wuw, 0.0f);
            acc[2*pr2]     += fmaf(fvA, bA - tA, tA);
            const unsigned tBv = d ? q.y : q.x;
            const unsigned bBv = d ? q.z : q.y;
            const float tB  = FDOT2(as_h2(tBv), wuw, 0.0f);
            const float bB  = FDOT2(as_h2(bBv), wuw, 0.0f);
            acc[2*pr2 + 1] += fmaf(fvB, bB - tB, tB);
        }
    }

    const float a = prelu[0];
    #pragma unroll
    for (int j = 0; j < 4; ++j) {
        const float v = acc[j];
        out[((z0 + j) << 14) + (y << 7) + x] = (v >= 0.0f) ? v : a * v;
    }
}

// ---------------------------------------------------------------------------
// K3 fallback: r8 uint2 loop + w2-fold (runs if ws too small for quads).
// ---------------------------------------------------------------------------
__global__ __launch_bounds__(256) void k_bp3d_fb(const uint2* __restrict__ wcb4,
                                                 const float* __restrict__ prelu,
                                                 float* __restrict__ out) {
    __shared__ float sc[NPROJ], ss[NPROJ];
    const int tid = threadIdx.x;
    const int x   = tid & 127;
    const int y   = (blockIdx.x << 1) | (tid >> 7);
    const int z0  = blockIdx.y << 2;

    if (tid < NPROJ) {
        float s_, c_;
        sincosf((float)tid * (float)(2.0 * 3.14159265358979323846 / 96.0), &s_, &c_);
        sc[tid] = c_; ss[tid] = s_;
    }
    const float fx  = (float)x - 63.5f;
    const float fy  = (float)y - 63.5f;
    const float zlo = (float)z0 - 63.5f;
    float acc[4];
    #pragma unroll
    for (int j = 0; j < 4; ++j) acc[j] = 0.0f;
    __syncthreads();

    const uint2* bb = wcb4;
    for (int b = 0; b < NPROJ; ++b, bb += NPIX) {
        const float cb    = sc[b], sb = ss[b];
        const float t     = fmaf(fx, cb,  fy * sb);
        const float sdist = fmaf(fy, cb, -fx * sb);
        const float invr  = frcp(500.0f + t);
        const float pu    = fmaf(KPROJ * sdist, invr, 63.5f);
        const int   iu0   = (int)pu;
        const float fu    = ffract(pu);
        float w2 = 1000.0f * invr; w2 *= w2;
        const float Kz    = KPROJ * invr;
        const h2    wuw   = as_h2(pack2((1.0f - fu) * w2, fu * w2));
        int   off[4];
        float fv[4];
        #pragma unroll
        for (int j = 0; j < 4; ++j) {
            const float pv  = fmaf(Kz, zlo + (float)j, 63.5f);
            const int   iv0 = (int)pv;
            fv[j]  = ffract(pv);
            off[j] = (iv0 << 7) + iu0;
        }
        uint2 g[4];
        #pragma unroll
        for (int j = 0; j < 4; ++j) g[j] = bb[off[j]];
        #pragma unroll
        for (int j = 0; j < 4; ++j) {
            const float top = FDOT2(as_h2(g[j].x), wuw, 0.0f);
            const float bot = FDOT2(as_h2(g[j].y), wuw, 0.0f);
            acc[j] += fmaf(fv[j], bot - top, top);
        }
    }
    const float a = prelu[0];
    #pragma unroll
    for (int j = 0; j < 4; ++j) {
        const float v = acc[j];
        out[((z0 + j) << 14) + (y << 7) + x] = (v >= 0.0f) ? v : a * v;
    }
}

// ---------------------------------------------------------------------------
extern "C" void kernel_launch(void* const* d_in, const int* in_sizes, int n_in,
                              void* d_out, int out_size, void* d_ws, size_t ws_size,
                              hipStream_t stream) {
    const float* sino  = (const float*)d_in[0];   // (1,1,96,96,192)
    const float* wgt   = (const float*)d_in[1];   // (1,96,96,192)
    const float* prelu = (const float*)d_in[2];   // (1,)
    float* out = (float*)d_out;                   // 128^3 floats

    const size_t deriv_bytes = (size_t)NPROJ * SLICE * 4;       // 7.08 MB
    const size_t quad_bytes  = (size_t)NPROJ * NPIX * 16;       // 25.17 MB
    unsigned* derivp = (unsigned*)d_ws;
    unsigned* store  = derivp + NPROJ * SLICE;

    k_deriv<<<dim3(NPROJ * NANG), dim3(192), 0, stream>>>(sino, wgt, derivp);

    if (ws_size >= deriv_bytes + quad_bytes) {
        k_bp2d_t<1><<<dim3(NPROJ, 32), dim3(256), 0, stream>>>(derivp, store);
        k_bp3d_q<<<dim3(64, 32), dim3(256), 0, stream>>>((const uint4*)store, prelu, out);
    } else {
        k_bp2d_t<0><<<dim3(NPROJ, 32), dim3(256), 0, stream>>>(derivp, store);
        k_bp3d_fb<<<dim3(64, 32), dim3(256), 0, stream>>>((const uint2*)store, prelu, out);
    }
}